// Round 1
// baseline (307.700 us; speedup 1.0000x reference)
//
#include <hip/hip_runtime.h>
#include <math.h>

#define HW   256
#define BCN  12      // B*C
#define NF   32      // filters actually used (last of 33 dropped)
#define UH   129     // Hermitian half + Nyquist rows stored
#define UPAD 136     // padded u-extent of Z (64B-aligned tiles)
#define RP   258     // padded LDS row stride (float2 units)
#define R_TOTAL 25165824  // BCN*HW*HW*NF

// ---------- 256-point complex FFT in LDS, one wave (64 lanes) per row ------
// tw[k] = (cos(2*pi*k/256), sin(2*pi*k/256)); dsign=-1 forward (numpy fft),
// +1 inverse (unnormalized; 1/65536 folded into filters).
__device__ __forceinline__ void fft256(float2* a, int lane, float dsign,
                                       const float2* tw) {
  __syncthreads();
#pragma unroll
  for (int q = 0; q < 4; ++q) {
    int k = lane + (q << 6);
    int r = __brev((unsigned)k) >> 24;
    if (r > k) { float2 t = a[k]; a[k] = a[r]; a[r] = t; }
  }
  int sh = 0;
  for (int len = 2; len <= 256; len <<= 1) {
    int half = len >> 1;
    int tstep = 256 >> (sh + 1);
    __syncthreads();
#pragma unroll
    for (int q = 0; q < 2; ++q) {
      int k = lane + (q << 6);
      int off = k & (half - 1);
      int blk = k >> sh;
      int i0 = (blk << (sh + 1)) | off;
      int i1 = i0 + half;
      float2 w = tw[off * tstep];
      float wy = w.y * dsign;
      float2 x1 = a[i1];
      float2 x0 = a[i0];
      float tx = w.x * x1.x - wy * x1.y;
      float ty = w.x * x1.y + wy * x1.x;
      a[i0] = make_float2(x0.x + tx, x0.y + ty);
      a[i1] = make_float2(x0.x - tx, x0.y - ty);
    }
    ++sh;
  }
  __syncthreads();
}

__device__ __forceinline__ void init_tw(float2* tw, int tid) {
  if (tid < 128) {
    float s, c;
    sincospif((float)tid * (1.0f / 128.0f), &s, &c);
    tw[tid] = make_float2(c, s);
  }
}

// ---------- prep: symmetrized, rms- and 1/(HW)-scaled filters --------------
// psi[j][u][v] = (f[j][u][v] + f[j][-u][-v]) * 0.5 / rms[j] / 65536, u<=128
__global__ void k_prep(const float* __restrict__ filt,
                       const float* __restrict__ rms,
                       float* __restrict__ psi) {
  int u = blockIdx.x;        // 0..128
  int j = blockIdx.y;        // 0..31
  int v = threadIdx.x;       // 0..255
  int u2 = (HW - u) & 255;
  int v2 = (HW - v) & 255;
  float a = filt[(j * HW + u) * HW + v];
  float b = filt[(j * HW + u2) * HW + v2];
  psi[(j * UH + u) * HW + v] = (a + b) * 0.5f * (1.0f / 65536.0f) / rms[j];
}

// ---------- forward FFT over w (rows). inp 0: target-prediction, 1: radius -
__global__ void k_fwd_rows(const float* __restrict__ tg,
                           const float* __restrict__ pr,
                           const float* __restrict__ ir,
                           float2* __restrict__ Xf) {
  __shared__ float2 rows[4][RP];
  __shared__ float2 tw[128];
  int tid = threadIdx.x, lane = tid & 63, wv = tid >> 6;
  init_tw(tw, tid);
  int inp = blockIdx.y;
  int row0 = blockIdx.x * 4;            // row = bc*256 + h
  for (int i = tid; i < 4 * HW; i += 256) {
    int rr = i >> 8, v = i & 255;
    int idx = (row0 + rr) * HW + v;
    float val = (inp == 0) ? (tg[idx] - pr[idx]) : ir[idx];
    rows[rr][v] = make_float2(val, 0.0f);
  }
  fft256(rows[wv], lane, -1.0f, tw);
  float2* dst = Xf + (size_t)inp * BCN * HW * HW;
  for (int i = tid; i < 4 * HW; i += 256) {
    int rr = i >> 8, v = i & 255;
    dst[(size_t)(row0 + rr) * HW + v] = rows[rr][v];
  }
}

// ---------- forward FFT over h (cols), in place, 16 cols per block ---------
__global__ void k_fwd_cols(float2* __restrict__ Xf) {
  __shared__ float2 cols[16][RP];
  __shared__ float2 tw[128];
  int tid = threadIdx.x, lane = tid & 63, wv = tid >> 6;
  init_tw(tw, tid);
  int inp = blockIdx.y;
  int bc = blockIdx.x >> 4;
  int w0 = (blockIdx.x & 15) << 4;
  float2* base = Xf + (size_t)(inp * BCN + bc) * HW * HW;
  for (int i = tid; i < 16 * HW; i += 256) {
    int u = i >> 4, ww = i & 15;
    cols[ww][u] = base[(size_t)u * HW + w0 + ww];
  }
  for (int r = 0; r < 4; ++r) fft256(cols[r * 4 + wv], lane, -1.0f, tw);
  for (int i = tid; i < 16 * HW; i += 256) {
    int u = i >> 4, ww = i & 15;
    base[(size_t)u * HW + w0 + ww] = cols[ww][u];
  }
}

// ---------- B1: Y = Xf * psi_sym, row-IFFT (u<=128), transposed store ------
// Z layout: [inp][bcl][j][v=256][UPAD]
__global__ void k_b1(const float2* __restrict__ Xf,
                     const float* __restrict__ psi,
                     float2* __restrict__ Z, int bc0, int bcc) {
  __shared__ float2 rows[8][RP];
  __shared__ float2 tw[128];
  int tid = threadIdx.x, lane = tid & 63, wv = tid >> 6;
  init_tw(tw, tid);
  int u0 = blockIdx.x * 8;              // 0..128 step 8 (17 tiles)
  int bcl = blockIdx.y;
  int bc = bc0 + bcl;
  int j = blockIdx.z >> 1;
  int inp = blockIdx.z & 1;
  const float2* xb = Xf + (size_t)(inp * BCN + bc) * HW * HW;
  const float* pb = psi + (size_t)j * UH * HW;
  for (int i = tid; i < 8 * HW; i += 256) {
    int rr = i >> 8, v = i & 255;
    int u = u0 + rr;
    float2 val = make_float2(0.0f, 0.0f);
    if (u < UH) {
      float2 x = xb[(size_t)u * HW + v];
      float p = pb[(size_t)u * HW + v];
      val = make_float2(x.x * p, x.y * p);
    }
    rows[rr][v] = val;
  }
  fft256(rows[wv], lane, 1.0f, tw);
  fft256(rows[4 + wv], lane, 1.0f, tw);
  float2* zb = Z + ((size_t)(inp * bcc + bcl) * NF + j) * HW * UPAD;
  for (int i = tid; i < 8 * HW; i += 256) {
    int uu = i & 7, v = i >> 3;
    int u = u0 + uu;
    if (u < UH) zb[(size_t)v * UPAD + u] = rows[uu][v];
  }
}

// ---------- B2: Hermitian-packed col-IFFT + pointwise R + partial sums -----
__global__ void k_b2(const float2* __restrict__ Z, float* __restrict__ out,
                     double* __restrict__ part, int bc0, int bcc) {
  __shared__ float2 work[4][RP];
  __shared__ float Rt[HW * 33];
  __shared__ double red[256];
  __shared__ float2 tw[128];
  int tid = threadIdx.x, lane = tid & 63, wv = tid >> 6;
  init_tw(tw, tid);
  int w = blockIdx.x;
  int bcl = blockIdx.y;
  int bc = bc0 + bcl;
  double lsum = 0.0, lsq = 0.0;
  for (int r8 = 0; r8 < 8; ++r8) {
    int j = r8 * 4 + wv;
    const float2* zd = Z + (((size_t)(0 * bcc + bcl) * NF + j) * HW + w) * UPAD;
    const float2* zr = Z + (((size_t)(1 * bcc + bcl) * NF + j) * HW + w) * UPAD;
    float2* wk = work[wv];
    // Q[u] = Zd_full[u] + i*Zr_full[u]; Hermitian extension for u>128.
    {
      float2 d = zd[lane], r = zr[lane];
      wk[lane] = make_float2(d.x - r.y, d.y + r.x);
      d = zd[64 + lane]; r = zr[64 + lane];
      wk[64 + lane] = make_float2(d.x - r.y, d.y + r.x);
      int m2 = (lane == 0) ? 128 : (128 - lane);
      d = zd[m2]; r = zr[m2];
      wk[128 + lane] = (lane == 0) ? make_float2(d.x - r.y, d.y + r.x)
                                   : make_float2(d.x + r.y, r.x - d.y);
      int m3 = 64 - lane;
      d = zd[m3]; r = zr[m3];
      wk[192 + lane] = make_float2(d.x + r.y, r.x - d.y);
    }
    fft256(wk, lane, 1.0f, tw);
#pragma unroll
    for (int qq = 0; qq < 4; ++qq) {
      int h = lane + (qq << 6);
      float cd = wk[h].x;      // diff coeffs (already /rms, /HW)
      float cr = wk[h].y;      // radius coeffs
      float t1 = fmaxf(fabsf(cd) - cr, 0.0f);
      float Rv = 1.0f - fmaxf(1.0f - t1, 0.0f);
      Rt[h * 33 + j] = Rv;
      lsum += Rv;
      lsq += (double)Rv * (double)Rv;
    }
  }
  __syncthreads();
  float* ob = out + (size_t)bc * (HW * HW * NF);
  for (int i = tid; i < HW * NF; i += 256) {
    int h = i >> 5, j = i & 31;
    ob[((size_t)h * HW + w) * NF + j] = Rt[h * 33 + j];
  }
  red[tid] = lsum;
  __syncthreads();
  for (int s = 128; s > 0; s >>= 1) {
    if (tid < s) red[tid] += red[tid + s];
    __syncthreads();
  }
  double bs = red[0];
  __syncthreads();
  red[tid] = lsq;
  __syncthreads();
  for (int s = 128; s > 0; s >>= 1) {
    if (tid < s) red[tid] += red[tid + s];
    __syncthreads();
  }
  if (tid == 0) {
    part[((size_t)bc * HW + w) * 2 + 0] = bs;
    part[((size_t)bc * HW + w) * 2 + 1] = red[0];
  }
}

// ---------- finalize: deterministic mean/std (ddof=1) per batch ------------
__global__ void k_fin(const double* __restrict__ part, float* __restrict__ out) {
  __shared__ double red[256];
  int b = blockIdx.x, t = threadIdx.x;
  double s = 0.0, q = 0.0;
  for (int i = t; i < 768; i += 256) {   // 3 bc * 256 w slots per batch
    s += part[((size_t)b * 768 + i) * 2 + 0];
    q += part[((size_t)b * 768 + i) * 2 + 1];
  }
  red[t] = s;
  __syncthreads();
  for (int k = 128; k > 0; k >>= 1) {
    if (t < k) red[t] += red[t + k];
    __syncthreads();
  }
  double S = red[0];
  __syncthreads();
  red[t] = q;
  __syncthreads();
  for (int k = 128; k > 0; k >>= 1) {
    if (t < k) red[t] += red[t + k];
    __syncthreads();
  }
  if (t == 0) {
    const double N = 6291456.0;          // C*H*W*NF
    double m = S / N;
    double var = (red[0] - S * S / N) / (N - 1.0);
    out[R_TOTAL + b] = (float)m;
    out[R_TOTAL + 4 + b] = (float)(var > 0.0 ? sqrt(var) : 0.0);
  }
}

extern "C" void kernel_launch(void* const* d_in, const int* in_sizes, int n_in,
                              void* d_out, int out_size, void* d_ws, size_t ws_size,
                              hipStream_t stream) {
  (void)in_sizes; (void)n_in; (void)out_size;
  const float* tg = (const float*)d_in[0];
  const float* pr = (const float*)d_in[1];
  const float* ir = (const float*)d_in[2];
  const float* filt = (const float*)d_in[3];
  const float* rms = (const float*)d_in[4];
  float* out = (float*)d_out;

  char* ws = (char*)d_ws;
  // layout: part (3072*2 doubles) | psi | Xf | Z
  double* part = (double*)(ws + 128);
  const size_t partB = (size_t)BCN * HW * 2 * sizeof(double);      // 49152
  float* psi = (float*)(ws + 128 + partB);
  const size_t psiB = (size_t)NF * UH * HW * sizeof(float);        // 4227072
  float2* Xf = (float2*)(ws + 128 + partB + psiB);
  const size_t xfB = (size_t)2 * BCN * HW * HW * sizeof(float2);   // 12582912
  float2* Zb = (float2*)(ws + 128 + partB + psiB + xfB);
  const size_t fixedB = 128 + partB + psiB + xfB;
  const size_t zPerBc = (size_t)2 * NF * HW * UPAD * sizeof(float2); // 17825792

  int bcc = 1;
  const int cand[5] = {12, 6, 4, 3, 2};
  for (int i = 0; i < 5; ++i) {
    if (fixedB + (size_t)cand[i] * zPerBc <= ws_size) { bcc = cand[i]; break; }
  }

  k_prep<<<dim3(UH, NF), 256, 0, stream>>>(filt, rms, psi);
  k_fwd_rows<<<dim3(BCN * HW / 4, 2), 256, 0, stream>>>(tg, pr, ir, Xf);
  k_fwd_cols<<<dim3(BCN * 16, 2), 256, 0, stream>>>(Xf);

  int nch = BCN / bcc;
  for (int c = 0; c < nch; ++c) {
    int bc0 = c * bcc;
    k_b1<<<dim3(17, bcc, NF * 2), 256, 0, stream>>>(Xf, psi, Zb, bc0, bcc);
    k_b2<<<dim3(HW, bcc), 256, 0, stream>>>(Zb, out, part, bc0, bcc);
  }
  k_fin<<<4, 256, 0, stream>>>(part, out);
}

// Round 2
// 215.740 us; speedup vs baseline: 1.4263x; 1.4263x over previous
//
#include <hip/hip_runtime.h>
#include <math.h>

#define HW 256
#define BCN 12                  // B*C
#define NF 32                   // filters used (last of 33 dropped)
#define R_TOTAL 25165824        // BCN*HW*HW*NF

// ---------------- complex helpers ----------------
__device__ __forceinline__ float2 cadd(float2 a, float2 b){return make_float2(a.x+b.x,a.y+b.y);}
__device__ __forceinline__ float2 csub(float2 a, float2 b){return make_float2(a.x-b.x,a.y-b.y);}
__device__ __forceinline__ float2 cmul(float2 a, float2 b){return make_float2(a.x*b.x-a.y*b.y, a.x*b.y+a.y*b.x);}
__device__ __forceinline__ float2 shfl_xor2(float2 v, int m){
  return make_float2(__shfl_xor(v.x,m,64), __shfl_xor(v.y,m,64));
}

// twiddles per lane, computed once: tw[0..5] for stages M=8,16,32,64,128,256
// W_M^j = e^{sgn*2pi i j/M}; forward sgn=-1, inverse sgn=+1.
__device__ __forceinline__ void make_tw(float2 tw[6], int lane, float sgn){
  float s,c;
  sincospif((float)(lane&3)*0.25f,&s,&c);     tw[0]=make_float2(c,sgn*s);
  sincospif((float)(lane&7)*0.125f,&s,&c);    tw[1]=make_float2(c,sgn*s);
  sincospif((float)(lane&15)*0.0625f,&s,&c);  tw[2]=make_float2(c,sgn*s);
  sincospif((float)(lane&31)*0.03125f,&s,&c); tw[3]=make_float2(c,sgn*s);
  sincospif((float)lane*(1.0f/64.0f),&s,&c);  tw[4]=make_float2(c,sgn*s);
  sincospif((float)lane*(1.0f/128.0f),&s,&c); tw[5]=make_float2(c,sgn*s);
}

// ---- forward 256-pt FFT, DIF. Input: e[r] = x[64r+lane] (natural).
// Output: position p=64r+lane holds F[brev8(p)]. Lane writes chunk at
// 4*brev6(lane): c[k] = e[brev2(k)] -> {e0,e2,e1,e3}.
__device__ __forceinline__ void fftfwd(float2 e[4], const float2 tw[6], int lane){
  float2 d, t;
  // M=256 (s=128): pairs (0,2),(1,3); pair1 twiddle *= -i
  d = csub(e[0],e[2]); e[0]=cadd(e[0],e[2]); t = cmul(d,tw[5]);
  d = csub(e[1],e[3]); e[1]=cadd(e[1],e[3]); d = cmul(d,tw[5]);
  e[2]=t; e[3]=make_float2(d.y,-d.x);
  // M=128 (s=64): pairs (0,1),(2,3)
  d = csub(e[0],e[1]); e[0]=cadd(e[0],e[1]); e[1]=cmul(d,tw[4]);
  d = csub(e[2],e[3]); e[2]=cadd(e[2],e[3]); e[3]=cmul(d,tw[4]);
  // cross-lane s=32,16,8,4
#pragma unroll
  for(int si=0; si<4; ++si){
    int mask = 32>>si;
    float2 W = tw[3-si];
#pragma unroll
    for(int r=0;r<4;++r){
      float2 o = shfl_xor2(e[r],mask);
      float2 lo = cadd(e[r],o);
      float2 hi = cmul(csub(o,e[r]),W);
      e[r] = (lane&mask)? hi : lo;
    }
  }
  // s=2: W4^{lane&1} = 1 or -i
#pragma unroll
  for(int r=0;r<4;++r){
    float2 o = shfl_xor2(e[r],2);
    float2 lo = cadd(e[r],o);
    float2 d2 = csub(o,e[r]);
    if(lane&1) d2 = make_float2(d2.y,-d2.x);
    e[r] = (lane&2)? d2 : lo;
  }
  // s=1: W=1
#pragma unroll
  for(int r=0;r<4;++r){
    float2 o = shfl_xor2(e[r],1);
    e[r] = (lane&1)? csub(o,e[r]) : cadd(e[r],o);
  }
}

// ---- inverse 256-pt FFT (unnormalized), DIT. Input: e[r] = F[4*brev6(lane)+brev2(r)]
// i.e. chunk c[0..3] -> e0=c0,e1=c2,e2=c1,e3=c3. Output: e[r] = y[64r+lane] (natural).
__device__ __forceinline__ void fftinv(float2 e[4], const float2 tw[6], int lane){
  // s=1
#pragma unroll
  for(int r=0;r<4;++r){
    float2 o = shfl_xor2(e[r],1);
    e[r] = (lane&1)? csub(o,e[r]) : cadd(e[r],o);
  }
  // s=2: W = +i when (lane&1)
#pragma unroll
  for(int r=0;r<4;++r){
    float2 o = shfl_xor2(e[r],2);
    bool hi = (lane&2)!=0;
    float2 B = hi? e[r] : o;
    float2 A = hi? o : e[r];
    if(lane&1) B = make_float2(-B.y,B.x);
    e[r] = hi? csub(A,B) : cadd(A,B);
  }
  // s=4,8,16,32
#pragma unroll
  for(int si=0; si<4; ++si){
    int mask = 4<<si;
    float2 W = tw[si];
#pragma unroll
    for(int r=0;r<4;++r){
      float2 o = shfl_xor2(e[r],mask);
      bool hi = (lane&mask)!=0;
      float2 B = hi? e[r] : o;
      float2 A = hi? o : e[r];
      float2 t = cmul(W,B);
      e[r] = hi? csub(A,t) : cadd(A,t);
    }
  }
  // s=64: pairs (0,1),(2,3)
  float2 t = cmul(tw[4],e[1]); e[1]=csub(e[0],t); e[0]=cadd(e[0],t);
  t = cmul(tw[4],e[3]); e[3]=csub(e[2],t); e[2]=cadd(e[2],t);
  // s=128: pairs (0,2),(1,3); pair1 twiddle *= +i
  t = cmul(tw[5],e[2]); e[2]=csub(e[0],t); e[0]=cadd(e[0],t);
  t = cmul(tw[5],e[3]); t = make_float2(-t.y,t.x);
  e[3]=csub(e[1],t); e[1]=cadd(e[1],t);
}

// ---------- prep: psi[j][u][v] = (f[u,v]+f[-u,-v])*0.5/rms[j]/65536 ----------
__global__ __launch_bounds__(256) void k_prep(const float* __restrict__ filt,
                                              const float* __restrict__ rms,
                                              float* __restrict__ psi){
  int u = blockIdx.x, j = blockIdx.y, v = threadIdx.x;
  int u2 = (HW-u)&255, v2 = (HW-v)&255;
  float a = filt[((size_t)j*HW+u)*HW+v];
  float b = filt[((size_t)j*HW+u2)*HW+v2];
  psi[((size_t)j*HW+u)*HW+v] = (a+b)*0.5f*(1.0f/65536.0f)/rms[j];
}

// ---------- fwd rows: xc=(tg-pr)+i*ir, FFT over w -> X1[bc][h][vhat] ----------
__global__ __launch_bounds__(256) void k_fwd_rows(const float* __restrict__ tg,
                                                  const float* __restrict__ pr,
                                                  const float* __restrict__ ir,
                                                  float2* __restrict__ X1){
  int tid=threadIdx.x, lane=tid&63, wv=tid>>6;
  float2 tw[6]; make_tw(tw,lane,-1.0f);
  int bc = blockIdx.x>>6;
  int h  = ((blockIdx.x&63)<<2)|wv;
  size_t base = ((size_t)bc*HW+h)*HW;
  float2 e[4];
#pragma unroll
  for(int r=0;r<4;++r){
    int wd = lane+(r<<6);
    e[r] = make_float2(tg[base+wd]-pr[base+wd], ir[base+wd]);
  }
  fftfwd(e,tw,lane);
  int cb = __brev((unsigned)lane)>>26;
  float4* dst = (float4*)(X1 + base + (cb<<2));
  dst[0]=make_float4(e[0].x,e[0].y,e[2].x,e[2].y);
  dst[1]=make_float4(e[1].x,e[1].y,e[3].x,e[3].y);
}

// ---------- fwd cols: FFT over h -> T2[bc][vhat][uhat] ----------
__global__ __launch_bounds__(256) void k_fwd_cols(const float2* __restrict__ X1,
                                                  float2* __restrict__ T2){
  int tid=threadIdx.x, lane=tid&63, wv=tid>>6;
  float2 tw[6]; make_tw(tw,lane,-1.0f);
  int bc = blockIdx.x>>5;
  int vt = (blockIdx.x&31)<<3;           // 8 v per block (L1 reuse of 32B sectors)
  int cb = __brev((unsigned)lane)>>26;
  for(int q=0;q<2;++q){
    int v = vt + (wv<<1) + q;
    float2 e[4];
#pragma unroll
    for(int r=0;r<4;++r)
      e[r] = X1[((size_t)bc*HW + (r<<6)+lane)*HW + v];
    fftfwd(e,tw,lane);
    float4* dst = (float4*)(T2 + ((size_t)bc*HW+v)*HW + (cb<<2));
    dst[0]=make_float4(e[0].x,e[0].y,e[2].x,e[2].y);
    dst[1]=make_float4(e[1].x,e[1].y,e[3].x,e[3].y);
  }
}

// ---------- B1: Y = T2*psi, inverse FFT over u -> Z[bcl][j][h][vhat] ----------
__global__ __launch_bounds__(256) void k_b1(const float2* __restrict__ T2,
                                            const float* __restrict__ psi,
                                            float2* __restrict__ Z,
                                            int bc0){
  int tid=threadIdx.x, lane=tid&63, wv=tid>>6;
  float2 tw[6]; make_tw(tw,lane,+1.0f);
  int vt = blockIdx.x<<4;
  int j  = blockIdx.y;
  int bcl= blockIdx.z;
  int bc = bc0 + bcl;
  int cb = __brev((unsigned)lane)>>26;
  int u0 = cb<<2;
  int vb = vt + (wv<<2);
  const float*  pb = psi + ((size_t)j*HW + u0)*HW;
  const float2* tb = T2 + (size_t)bc*HW*HW;
  float2 o00,o01,o02,o03, o10,o11,o12,o13, o20,o21,o22,o23, o30,o31,o32,o33;
#pragma unroll
  for(int q=0;q<4;++q){
    int v = vb + q;
    const float4* src = (const float4*)(tb + (size_t)v*HW + u0);
    float4 A = src[0], B = src[1];
    float p0 = pb[v], p1 = pb[HW+v], p2 = pb[2*HW+v], p3 = pb[3*HW+v];
    float2 e[4];
    e[0]=make_float2(A.x*p0, A.y*p0);
    e[2]=make_float2(A.z*p1, A.w*p1);
    e[1]=make_float2(B.x*p2, B.y*p2);
    e[3]=make_float2(B.z*p3, B.w*p3);
    fftinv(e,tw,lane);
    if(q==0){o00=e[0];o10=e[1];o20=e[2];o30=e[3];}
    else if(q==1){o01=e[0];o11=e[1];o21=e[2];o31=e[3];}
    else if(q==2){o02=e[0];o12=e[1];o22=e[2];o32=e[3];}
    else {o03=e[0];o13=e[1];o23=e[2];o33=e[3];}
  }
  float2* zb = Z + (size_t)(bcl*NF + j)*HW*HW;
  float4* d0 = (float4*)(zb + (size_t)(lane      )*HW + vb);
  d0[0]=make_float4(o00.x,o00.y,o01.x,o01.y); d0[1]=make_float4(o02.x,o02.y,o03.x,o03.y);
  float4* d1 = (float4*)(zb + (size_t)( 64+lane  )*HW + vb);
  d1[0]=make_float4(o10.x,o10.y,o11.x,o11.y); d1[1]=make_float4(o12.x,o12.y,o13.x,o13.y);
  float4* d2 = (float4*)(zb + (size_t)(128+lane  )*HW + vb);
  d2[0]=make_float4(o20.x,o20.y,o21.x,o21.y); d2[1]=make_float4(o22.x,o22.y,o23.x,o23.y);
  float4* d3 = (float4*)(zb + (size_t)(192+lane  )*HW + vb);
  d3[0]=make_float4(o30.x,o30.y,o31.x,o31.y); d3[1]=make_float4(o32.x,o32.y,o33.x,o33.y);
}

// ---------- B2: inverse FFT over v, pointwise R, transpose, partial sums ----------
__global__ __launch_bounds__(256) void k_b2(const float2* __restrict__ Z,
                                            float* __restrict__ out,
                                            double* __restrict__ part,
                                            int bc0){
  __shared__ float Rt[16*260];           // [jloc][w], conflict-free both sides
  __shared__ double redS[4], redQ[4];
  int tid=threadIdx.x, lane=tid&63, wv=tid>>6;
  float2 tw[6]; make_tw(tw,lane,+1.0f);
  int h = blockIdx.x;
  int bcl = blockIdx.y;
  int bc = bc0 + bcl;
  int cb = __brev((unsigned)lane)>>26;
  double lsum=0.0, lsq=0.0;
  const float2* zb = Z + (size_t)bcl*NF*HW*HW + (size_t)h*HW;
  float* ob = out + (size_t)bc*(HW*HW*NF) + (size_t)h*(HW*NF);
  for(int jh=0;jh<2;++jh){
    if(jh) __syncthreads();
#pragma unroll
    for(int q=0;q<4;++q){
      int jl = (wv<<2)+q;
      int j  = (jh<<4)+jl;
      const float4* src = (const float4*)(zb + (size_t)j*HW*HW + (cb<<2));
      float4 A=src[0], B=src[1];
      float2 e[4];
      e[0]=make_float2(A.x,A.y);
      e[2]=make_float2(A.z,A.w);
      e[1]=make_float2(B.x,B.y);
      e[3]=make_float2(B.z,B.w);
      fftinv(e,tw,lane);
#pragma unroll
      for(int r=0;r<4;++r){
        float cd = e[r].x, cr = e[r].y;
        float t1 = fmaxf(fabsf(cd)-cr, 0.0f);
        float Rv = 1.0f - fmaxf(1.0f-t1, 0.0f);
        Rt[jl*260 + (r<<6)+lane] = Rv;
        lsum += Rv; lsq += (double)Rv*(double)Rv;
      }
    }
    __syncthreads();
    float vals[16];
#pragma unroll
    for(int k=0;k<16;++k) vals[k]=Rt[k*260+tid];
    float4* dst = (float4*)(ob + (size_t)tid*NF + (jh<<4));
    dst[0]=make_float4(vals[0],vals[1],vals[2],vals[3]);
    dst[1]=make_float4(vals[4],vals[5],vals[6],vals[7]);
    dst[2]=make_float4(vals[8],vals[9],vals[10],vals[11]);
    dst[3]=make_float4(vals[12],vals[13],vals[14],vals[15]);
  }
#pragma unroll
  for(int m=32;m>=1;m>>=1){
    lsum += __shfl_xor(lsum,m,64);
    lsq  += __shfl_xor(lsq,m,64);
  }
  if(lane==0){ redS[wv]=lsum; redQ[wv]=lsq; }
  __syncthreads();
  if(tid==0){
    double S=redS[0]+redS[1]+redS[2]+redS[3];
    double Q=redQ[0]+redQ[1]+redQ[2]+redQ[3];
    part[((size_t)bc*HW+h)*2+0]=S;
    part[((size_t)bc*HW+h)*2+1]=Q;
  }
}

// ---------- finalize: deterministic mean/std (ddof=1) per batch ----------
__global__ __launch_bounds__(256) void k_fin(const double* __restrict__ part,
                                             float* __restrict__ out){
  __shared__ double red[256];
  int b = blockIdx.x, t = threadIdx.x;
  double s=0.0, q=0.0;
  for(int i=t;i<768;i+=256){
    s += part[((size_t)b*768+i)*2+0];
    q += part[((size_t)b*768+i)*2+1];
  }
  red[t]=s; __syncthreads();
  for(int k=128;k>0;k>>=1){ if(t<k) red[t]+=red[t+k]; __syncthreads(); }
  double S=red[0]; __syncthreads();
  red[t]=q; __syncthreads();
  for(int k=128;k>0;k>>=1){ if(t<k) red[t]+=red[t+k]; __syncthreads(); }
  if(t==0){
    const double N = 6291456.0;          // C*H*W*NF
    double m = S/N;
    double var = (red[0] - S*S/N)/(N-1.0);
    out[R_TOTAL+b] = (float)m;
    out[R_TOTAL+4+b] = (float)(var>0.0? sqrt(var):0.0);
  }
}

extern "C" void kernel_launch(void* const* d_in, const int* in_sizes, int n_in,
                              void* d_out, int out_size, void* d_ws, size_t ws_size,
                              hipStream_t stream){
  (void)in_sizes; (void)n_in; (void)out_size;
  const float* tg   = (const float*)d_in[0];
  const float* pr   = (const float*)d_in[1];
  const float* ir   = (const float*)d_in[2];
  const float* filt = (const float*)d_in[3];
  const float* rms  = (const float*)d_in[4];
  float* out = (float*)d_out;

  char* ws = (char*)d_ws;
  double* part = (double*)(ws + 128);
  const size_t partB = (size_t)BCN*HW*2*sizeof(double);          // 49152
  float* psi = (float*)(ws + 128 + partB);
  const size_t psiB = (size_t)NF*HW*HW*sizeof(float);            // 8.39 MB
  float2* X1 = (float2*)(ws + 128 + partB + psiB);
  const size_t x1B = (size_t)BCN*HW*HW*sizeof(float2);           // 6.29 MB
  float2* T2 = (float2*)(ws + 128 + partB + psiB + x1B);
  const size_t t2B = x1B;
  float2* Zb = (float2*)(ws + 128 + partB + psiB + x1B + t2B);
  const size_t fixedB = 128 + partB + psiB + x1B + t2B;
  const size_t zPerBc = (size_t)NF*HW*HW*sizeof(float2);         // 16.78 MB

  int bcc = 1;
  const int cand[6] = {12,6,4,3,2,1};
  for(int i=0;i<6;++i){
    if(fixedB + (size_t)cand[i]*zPerBc <= ws_size){ bcc = cand[i]; break; }
  }

  k_prep<<<dim3(HW,NF), 256, 0, stream>>>(filt, rms, psi);
  k_fwd_rows<<<dim3(BCN*64), 256, 0, stream>>>(tg, pr, ir, X1);
  k_fwd_cols<<<dim3(BCN*32), 256, 0, stream>>>(X1, T2);

  int nch = BCN/bcc;
  for(int c=0;c<nch;++c){
    int bc0 = c*bcc;
    k_b1<<<dim3(16,NF,bcc), 256, 0, stream>>>(T2, psi, Zb, bc0);
    k_b2<<<dim3(HW,bcc), 256, 0, stream>>>(Zb, out, part, bc0);
  }
  k_fin<<<4, 256, 0, stream>>>(part, out);
}

// Round 3
// 161.097 us; speedup vs baseline: 1.9100x; 1.3392x over previous
//
#include <hip/hip_runtime.h>
#include <hip/hip_fp16.h>
#include <math.h>

#define HW 256
#define BCN 12                  // B*C
#define NF 32                   // filters used (last of 33 dropped)
#define R_TOTAL 25165824        // BCN*HW*HW*NF

// ---------------- fp16 pack helpers ----------------
__device__ __forceinline__ float2 h2f(unsigned u){
  return __half22float2(__builtin_bit_cast(__half2, u));
}
__device__ __forceinline__ unsigned f2h(float2 v){
  return __builtin_bit_cast(unsigned, __floats2half2_rn(v.x, v.y));
}

// ---------------- dual-complex (2-way ILP) helpers ----------------
// float4 = two independent complex values: (x,y) = FFT-A, (z,w) = FFT-B.
__device__ __forceinline__ float4 c4add(float4 a,float4 b){
  return make_float4(a.x+b.x,a.y+b.y,a.z+b.z,a.w+b.w);}
__device__ __forceinline__ float4 c4sub(float4 a,float4 b){
  return make_float4(a.x-b.x,a.y-b.y,a.z-b.z,a.w-b.w);}
__device__ __forceinline__ float4 c4mul(float2 w, float4 v){
  return make_float4(w.x*v.x - w.y*v.y, w.x*v.y + w.y*v.x,
                     w.x*v.z - w.y*v.w, w.x*v.w + w.y*v.z);}
__device__ __forceinline__ float4 rotmi(float4 v){   // * -i
  return make_float4(v.y,-v.x,v.w,-v.z);}
__device__ __forceinline__ float4 rotpi(float4 v){   // * +i
  return make_float4(-v.y,v.x,-v.w,v.z);}
__device__ __forceinline__ float4 shfl_xor4(float4 v,int m){
  return make_float4(__shfl_xor(v.x,m,64),__shfl_xor(v.y,m,64),
                     __shfl_xor(v.z,m,64),__shfl_xor(v.w,m,64));}

// twiddles per lane: tw[0..5] for stages M=8,16,32,64,128,256
__device__ __forceinline__ void make_tw(float2 tw[6], int lane, float sgn){
  float s,c;
  sincospif((float)(lane&3)*0.25f,&s,&c);     tw[0]=make_float2(c,sgn*s);
  sincospif((float)(lane&7)*0.125f,&s,&c);    tw[1]=make_float2(c,sgn*s);
  sincospif((float)(lane&15)*0.0625f,&s,&c);  tw[2]=make_float2(c,sgn*s);
  sincospif((float)(lane&31)*0.03125f,&s,&c); tw[3]=make_float2(c,sgn*s);
  sincospif((float)lane*(1.0f/64.0f),&s,&c);  tw[4]=make_float2(c,sgn*s);
  sincospif((float)lane*(1.0f/128.0f),&s,&c); tw[5]=make_float2(c,sgn*s);
}

// ---- forward 256-pt FFT ×2, DIF. Input: e[r] = x[64r+lane] (natural).
// Chunked natural-order store: at 4*brev6(lane), write {e0,e2,e1,e3}.
__device__ __forceinline__ void fftfwd4(float4 e[4], const float2 tw[6], int lane){
  float4 d,t;
  d = c4sub(e[0],e[2]); e[0]=c4add(e[0],e[2]); t = c4mul(tw[5],d);
  d = c4sub(e[1],e[3]); e[1]=c4add(e[1],e[3]); d = c4mul(tw[5],d);
  e[2]=t; e[3]=rotmi(d);
  d = c4sub(e[0],e[1]); e[0]=c4add(e[0],e[1]); e[1]=c4mul(tw[4],d);
  d = c4sub(e[2],e[3]); e[2]=c4add(e[2],e[3]); e[3]=c4mul(tw[4],d);
#pragma unroll
  for(int si=0; si<4; ++si){
    int mask = 32>>si;
    float2 W = tw[3-si];
#pragma unroll
    for(int r=0;r<4;++r){
      float4 o = shfl_xor4(e[r],mask);
      float4 lo = c4add(e[r],o);
      float4 hi = c4mul(W,c4sub(o,e[r]));
      e[r] = (lane&mask)? hi : lo;
    }
  }
#pragma unroll
  for(int r=0;r<4;++r){
    float4 o = shfl_xor4(e[r],2);
    float4 lo = c4add(e[r],o);
    float4 d2 = c4sub(o,e[r]);
    if(lane&1) d2 = rotmi(d2);
    e[r] = (lane&2)? d2 : lo;
  }
#pragma unroll
  for(int r=0;r<4;++r){
    float4 o = shfl_xor4(e[r],1);
    e[r] = (lane&1)? c4sub(o,e[r]) : c4add(e[r],o);
  }
}

// ---- inverse 256-pt FFT ×2 (unnormalized), DIT. Chunked natural-order
// load at 4*brev6(lane): e0=c0, e1=c2, e2=c1, e3=c3. Output natural.
__device__ __forceinline__ void fftinv4(float4 e[4], const float2 tw[6], int lane){
#pragma unroll
  for(int r=0;r<4;++r){
    float4 o = shfl_xor4(e[r],1);
    e[r] = (lane&1)? c4sub(o,e[r]) : c4add(e[r],o);
  }
#pragma unroll
  for(int r=0;r<4;++r){
    float4 o = shfl_xor4(e[r],2);
    bool hi = (lane&2)!=0;
    float4 B = hi? e[r] : o;
    float4 A = hi? o : e[r];
    if(lane&1) B = rotpi(B);
    e[r] = hi? c4sub(A,B) : c4add(A,B);
  }
#pragma unroll
  for(int si=0; si<4; ++si){
    int mask = 4<<si;
    float2 W = tw[si];
#pragma unroll
    for(int r=0;r<4;++r){
      float4 o = shfl_xor4(e[r],mask);
      bool hi = (lane&mask)!=0;
      float4 B = hi? e[r] : o;
      float4 A = hi? o : e[r];
      float4 t = c4mul(W,B);
      e[r] = hi? c4sub(A,t) : c4add(A,t);
    }
  }
  float4 t = c4mul(tw[4],e[1]); e[1]=c4sub(e[0],t); e[0]=c4add(e[0],t);
  t = c4mul(tw[4],e[3]); e[3]=c4sub(e[2],t); e[2]=c4add(e[2],t);
  t = c4mul(tw[5],e[2]); e[2]=c4sub(e[0],t); e[0]=c4add(e[0],t);
  t = c4mul(tw[5],e[3]); t = rotpi(t);
  e[3]=c4sub(e[1],t); e[1]=c4add(e[1],t);
}

// ---------- prep: psiP[j][v][u] = (f[u,v]+f[-u,-v])*0.5/rms[j], fp16, transposed
__global__ __launch_bounds__(256) void k_prep(const float* __restrict__ filt,
                                              const float* __restrict__ rms,
                                              __half* __restrict__ psiP){
  __shared__ float tile[32][257];
  int j = blockIdx.y, u0 = blockIdx.x<<5, tid = threadIdx.x;
  float rinv = 1.0f / rms[j];
  const float* fj = filt + (size_t)j*HW*HW;
#pragma unroll 4
  for(int k=0;k<32;++k){
    int u = u0+k, v = tid;
    int u2 = (HW-u)&255, v2 = (HW-v)&255;
    tile[k][v] = (fj[(size_t)u*HW+v] + fj[(size_t)u2*HW+v2])*0.5f*rinv;
  }
  __syncthreads();
  __half* pj = psiP + (size_t)j*HW*HW + u0;
#pragma unroll 4
  for(int it=0; it<32; ++it){
    int v = (it<<3) + (tid>>5), ul = tid&31;
    pj[(size_t)v*HW + ul] = __float2half(tile[ul][v]);
  }
}

// ---------- fwd rows: xc=(tg-pr)+i*ir, FFT over w -> X1[bc][h][v] (fp32) ----
__global__ __launch_bounds__(256) void k_fwd_rows(const float* __restrict__ tg,
                                                  const float* __restrict__ pr,
                                                  const float* __restrict__ ir,
                                                  float2* __restrict__ X1){
  int tid=threadIdx.x, lane=tid&63, wv=tid>>6;
  float2 tw[6]; make_tw(tw,lane,-1.0f);
  int bc = blockIdx.x>>5;
  int h0 = ((blockIdx.x&31)<<3) | (wv<<1);
  size_t b0 = ((size_t)bc*HW+h0)*HW;
  size_t b1 = b0 + HW;
  float4 e[4];
#pragma unroll
  for(int r=0;r<4;++r){
    int wd = lane+(r<<6);
    e[r] = make_float4(tg[b0+wd]-pr[b0+wd], ir[b0+wd],
                       tg[b1+wd]-pr[b1+wd], ir[b1+wd]);
  }
  fftfwd4(e,tw,lane);
  int cb = __brev((unsigned)lane)>>26;
  float4* d0 = (float4*)(X1 + b0 + (cb<<2));
  d0[0]=make_float4(e[0].x,e[0].y,e[2].x,e[2].y);
  d0[1]=make_float4(e[1].x,e[1].y,e[3].x,e[3].y);
  float4* d1 = (float4*)(X1 + b1 + (cb<<2));
  d1[0]=make_float4(e[0].z,e[0].w,e[2].z,e[2].w);
  d1[1]=make_float4(e[1].z,e[1].w,e[3].z,e[3].w);
}

// ---------- fwd cols: FFT over h, scale 1/65536 -> T2h[bc][v][u] (fp16) ----
__global__ __launch_bounds__(256) void k_fwd_cols(const float2* __restrict__ X1,
                                                  unsigned* __restrict__ T2h){
  int tid=threadIdx.x, lane=tid&63, wv=tid>>6;
  float2 tw[6]; make_tw(tw,lane,-1.0f);
  int bc = blockIdx.x>>5;
  int v0 = ((blockIdx.x&31)<<3) | (wv<<1);   // pair (v0, v0+1)
  float4 e[4];
#pragma unroll
  for(int r=0;r<4;++r)
    e[r] = *(const float4*)(X1 + ((size_t)bc*HW + (r<<6)+lane)*HW + v0);
  fftfwd4(e,tw,lane);
  const float s = 1.0f/65536.0f;
  int cb = __brev((unsigned)lane)>>26;
  unsigned* t0 = T2h + (size_t)bc*HW*HW + (size_t)v0*HW + (cb<<2);
  *(uint4*)t0 = make_uint4(f2h(make_float2(e[0].x*s,e[0].y*s)),
                           f2h(make_float2(e[2].x*s,e[2].y*s)),
                           f2h(make_float2(e[1].x*s,e[1].y*s)),
                           f2h(make_float2(e[3].x*s,e[3].y*s)));
  *(uint4*)(t0+HW) = make_uint4(f2h(make_float2(e[0].z*s,e[0].w*s)),
                                f2h(make_float2(e[2].z*s,e[2].w*s)),
                                f2h(make_float2(e[1].z*s,e[1].w*s)),
                                f2h(make_float2(e[3].z*s,e[3].w*s)));
}

// ---------- B1: Y = T2h*psiP, inverse FFT over u -> Zh[bcl*NF+j][h][v] fp16
__global__ __launch_bounds__(256) void k_b1(const unsigned* __restrict__ T2h,
                                            const __half* __restrict__ psiP,
                                            unsigned* __restrict__ Zh,
                                            int bc0){
  int tid=threadIdx.x, lane=tid&63, wv=tid>>6;
  float2 tw[6]; make_tw(tw,lane,+1.0f);
  int vt = blockIdx.x<<4;
  int j  = blockIdx.y;
  int bcl= blockIdx.z;
  int bc = bc0 + bcl;
  int cb = __brev((unsigned)lane)>>26;
  int u0 = cb<<2;
  int vb = vt + (wv<<2);
  const unsigned* tb  = T2h  + (size_t)bc*HW*HW + u0;
  const __half*   pjb = psiP + (size_t)j*HW*HW + u0;
  float4 ea[4], eb[4];
#pragma unroll
  for(int p=0;p<2;++p){
    int v0 = vb + (p<<1);
    uint4 tA = *(const uint4*)(tb + (size_t)v0*HW);
    uint4 tB = *(const uint4*)(tb + (size_t)(v0+1)*HW);
    uint2 puA = *(const uint2*)(pjb + (size_t)v0*HW);
    uint2 puB = *(const uint2*)(pjb + (size_t)(v0+1)*HW);
    float2 pA01 = h2f(puA.x), pA23 = h2f(puA.y);
    float2 pB01 = h2f(puB.x), pB23 = h2f(puB.y);
    float2 a0=h2f(tA.x), a1=h2f(tA.y), a2=h2f(tA.z), a3=h2f(tA.w);
    float2 c0=h2f(tB.x), c1=h2f(tB.y), c2=h2f(tB.z), c3=h2f(tB.w);
    float4* e = p? eb : ea;
    e[0]=make_float4(a0.x*pA01.x, a0.y*pA01.x, c0.x*pB01.x, c0.y*pB01.x);
    e[2]=make_float4(a1.x*pA01.y, a1.y*pA01.y, c1.x*pB01.y, c1.y*pB01.y);
    e[1]=make_float4(a2.x*pA23.x, a2.y*pA23.x, c2.x*pB23.x, c2.y*pB23.x);
    e[3]=make_float4(a3.x*pA23.y, a3.y*pA23.y, c3.x*pB23.y, c3.y*pB23.y);
    fftinv4(e,tw,lane);
  }
  unsigned* zb = Zh + (size_t)(bcl*NF + j)*HW*HW + vb;
#pragma unroll
  for(int r=0;r<4;++r){
    int h = (r<<6)+lane;
    *(uint4*)(zb + (size_t)h*HW) =
      make_uint4(f2h(make_float2(ea[r].x,ea[r].y)),
                 f2h(make_float2(ea[r].z,ea[r].w)),
                 f2h(make_float2(eb[r].x,eb[r].y)),
                 f2h(make_float2(eb[r].z,eb[r].w)));
  }
}

// ---------- B2: inverse FFT over v, pointwise R, transpose, partial sums ----
__global__ __launch_bounds__(256) void k_b2(const unsigned* __restrict__ Zh,
                                            float* __restrict__ out,
                                            double* __restrict__ part,
                                            int bc0){
  __shared__ float Rt[16*260];
  __shared__ double redS[4], redQ[4];
  int tid=threadIdx.x, lane=tid&63, wv=tid>>6;
  float2 tw[6]; make_tw(tw,lane,+1.0f);
  int h = blockIdx.x;
  int bcl = blockIdx.y;
  int bc = bc0 + bcl;
  int cb = __brev((unsigned)lane)>>26;
  double lsum=0.0, lsq=0.0;
  const unsigned* zb = Zh + (size_t)bcl*NF*HW*HW + (size_t)h*HW + (cb<<2);
  float* ob = out + (size_t)bc*(HW*HW*NF) + (size_t)h*(HW*NF);
  for(int jh=0;jh<2;++jh){
    if(jh) __syncthreads();
#pragma unroll
    for(int pp=0;pp<2;++pp){
      int jl0 = (wv<<2) + (pp<<1);
      int j0 = (jh<<4) + jl0;
      uint4 z0 = *(const uint4*)(zb + (size_t)j0*HW*HW);
      uint4 z1 = *(const uint4*)(zb + (size_t)(j0+1)*HW*HW);
      float2 a0=h2f(z0.x),a1=h2f(z0.y),a2=h2f(z0.z),a3=h2f(z0.w);
      float2 c0=h2f(z1.x),c1=h2f(z1.y),c2=h2f(z1.z),c3=h2f(z1.w);
      float4 e[4];
      e[0]=make_float4(a0.x,a0.y,c0.x,c0.y);
      e[2]=make_float4(a1.x,a1.y,c1.x,c1.y);
      e[1]=make_float4(a2.x,a2.y,c2.x,c2.y);
      e[3]=make_float4(a3.x,a3.y,c3.x,c3.y);
      fftinv4(e,tw,lane);
#pragma unroll
      for(int r=0;r<4;++r){
        int w = (r<<6)+lane;
        float t1 = fmaxf(fabsf(e[r].x)-e[r].y, 0.0f);
        float R0 = 1.0f - fmaxf(1.0f-t1, 0.0f);
        float t2 = fmaxf(fabsf(e[r].z)-e[r].w, 0.0f);
        float R1 = 1.0f - fmaxf(1.0f-t2, 0.0f);
        Rt[jl0*260 + w] = R0;
        Rt[(jl0+1)*260 + w] = R1;
        lsum += (double)R0 + (double)R1;
        lsq  += (double)R0*R0 + (double)R1*R1;
      }
    }
    __syncthreads();
    float vals[16];
#pragma unroll
    for(int k=0;k<16;++k) vals[k]=Rt[k*260+tid];
    float4* dst = (float4*)(ob + (size_t)tid*NF + (jh<<4));
    dst[0]=make_float4(vals[0],vals[1],vals[2],vals[3]);
    dst[1]=make_float4(vals[4],vals[5],vals[6],vals[7]);
    dst[2]=make_float4(vals[8],vals[9],vals[10],vals[11]);
    dst[3]=make_float4(vals[12],vals[13],vals[14],vals[15]);
  }
#pragma unroll
  for(int m=32;m>=1;m>>=1){
    lsum += __shfl_xor(lsum,m,64);
    lsq  += __shfl_xor(lsq,m,64);
  }
  if(lane==0){ redS[wv]=lsum; redQ[wv]=lsq; }
  __syncthreads();
  if(tid==0){
    double S=redS[0]+redS[1]+redS[2]+redS[3];
    double Q=redQ[0]+redQ[1]+redQ[2]+redQ[3];
    part[((size_t)bc*HW+h)*2+0]=S;
    part[((size_t)bc*HW+h)*2+1]=Q;
  }
}

// ---------- finalize: deterministic mean/std (ddof=1) per batch ----------
__global__ __launch_bounds__(256) void k_fin(const double* __restrict__ part,
                                             float* __restrict__ out){
  __shared__ double red[256];
  int b = blockIdx.x, t = threadIdx.x;
  double s=0.0, q=0.0;
  for(int i=t;i<768;i+=256){
    s += part[((size_t)b*768+i)*2+0];
    q += part[((size_t)b*768+i)*2+1];
  }
  red[t]=s; __syncthreads();
  for(int k=128;k>0;k>>=1){ if(t<k) red[t]+=red[t+k]; __syncthreads(); }
  double S=red[0]; __syncthreads();
  red[t]=q; __syncthreads();
  for(int k=128;k>0;k>>=1){ if(t<k) red[t]+=red[t+k]; __syncthreads(); }
  if(t==0){
    const double N = 6291456.0;          // C*H*W*NF
    double m = S/N;
    double var = (red[0] - S*S/N)/(N-1.0);
    out[R_TOTAL+b] = (float)m;
    out[R_TOTAL+4+b] = (float)(var>0.0? sqrt(var):0.0);
  }
}

extern "C" void kernel_launch(void* const* d_in, const int* in_sizes, int n_in,
                              void* d_out, int out_size, void* d_ws, size_t ws_size,
                              hipStream_t stream){
  (void)in_sizes; (void)n_in; (void)out_size;
  const float* tg   = (const float*)d_in[0];
  const float* pr   = (const float*)d_in[1];
  const float* ir   = (const float*)d_in[2];
  const float* filt = (const float*)d_in[3];
  const float* rms  = (const float*)d_in[4];
  float* out = (float*)d_out;

  char* ws = (char*)d_ws;
  double* part = (double*)(ws + 128);
  size_t off = 128 + (size_t)BCN*HW*2*sizeof(double);              // part: 49 KB
  __half* psiP = (__half*)(ws + off);  off += (size_t)NF*HW*HW*2;  // 4.19 MB
  float2* X1   = (float2*)(ws + off);  off += (size_t)BCN*HW*HW*8; // 6.29 MB
  unsigned* T2h= (unsigned*)(ws + off);off += (size_t)BCN*HW*HW*4; // 3.15 MB
  unsigned* Zh = (unsigned*)(ws + off);
  const size_t fixedB = off;
  const size_t zPerBc = (size_t)NF*HW*HW*4;                        // 8.39 MB

  int bcc = 1;
  const int cand[6] = {12,6,4,3,2,1};
  for(int i=0;i<6;++i){
    if(fixedB + (size_t)cand[i]*zPerBc <= ws_size){ bcc = cand[i]; break; }
  }

  k_prep<<<dim3(8,NF), 256, 0, stream>>>(filt, rms, psiP);
  k_fwd_rows<<<dim3(BCN*32), 256, 0, stream>>>(tg, pr, ir, X1);
  k_fwd_cols<<<dim3(BCN*32), 256, 0, stream>>>(X1, T2h);

  int nch = BCN/bcc;
  for(int c=0;c<nch;++c){
    int bc0 = c*bcc;
    k_b1<<<dim3(16,NF,bcc), 256, 0, stream>>>(T2h, psiP, Zh, bc0);
    k_b2<<<dim3(HW,bcc), 256, 0, stream>>>(Zh, out, part, bc0);
  }
  k_fin<<<4, 256, 0, stream>>>(part, out);
}

// Round 4
// 150.264 us; speedup vs baseline: 2.0477x; 1.0721x over previous
//
#include <hip/hip_runtime.h>
#include <hip/hip_fp16.h>
#include <math.h>

#define HW 256
#define BCN 12                  // B*C
#define NF 32                   // filters used (last of 33 dropped)
#define R_TOTAL 25165824        // BCN*HW*HW*NF

// ---------------- fp16 pack helpers ----------------
__device__ __forceinline__ float2 h2f(unsigned u){
  return __half22float2(__builtin_bit_cast(__half2, u));
}
__device__ __forceinline__ unsigned f2h(float2 v){
  return __builtin_bit_cast(unsigned, __floats2half2_rn(v.x, v.y));
}

// ---------------- dual-complex (2-way ILP) helpers ----------------
// float4 = two independent complex values: (x,y) = FFT-A, (z,w) = FFT-B.
__device__ __forceinline__ float4 c4add(float4 a,float4 b){
  return make_float4(a.x+b.x,a.y+b.y,a.z+b.z,a.w+b.w);}
__device__ __forceinline__ float4 c4sub(float4 a,float4 b){
  return make_float4(a.x-b.x,a.y-b.y,a.z-b.z,a.w-b.w);}
__device__ __forceinline__ float4 c4mul(float2 w, float4 v){
  return make_float4(w.x*v.x - w.y*v.y, w.x*v.y + w.y*v.x,
                     w.x*v.z - w.y*v.w, w.x*v.w + w.y*v.z);}
__device__ __forceinline__ float4 rotmi(float4 v){   // * -i
  return make_float4(v.y,-v.x,v.w,-v.z);}
__device__ __forceinline__ float4 rotpi(float4 v){   // * +i
  return make_float4(-v.y,v.x,-v.w,v.z);}
__device__ __forceinline__ float4 shfl_xor4(float4 v,int m){
  return make_float4(__shfl_xor(v.x,m,64),__shfl_xor(v.y,m,64),
                     __shfl_xor(v.z,m,64),__shfl_xor(v.w,m,64));}

// ---- DPP lane exchange (VALU pipe, not LDS pipe) ----
// xor1 = quad_perm(1,0,3,2)=0xB1, xor2 = quad_perm(2,3,0,1)=0x4E,
// xor8 = row_ror:8 = 0x128 ((i+8)%16 == i^8).
template<int CTRL>
__device__ __forceinline__ float dpp_f(float x){
  return __builtin_bit_cast(float,
    __builtin_amdgcn_update_dpp(0, __builtin_bit_cast(int, x), CTRL, 0xF, 0xF, true));
}
template<int CTRL>
__device__ __forceinline__ float4 dpp4(float4 v){
  return make_float4(dpp_f<CTRL>(v.x), dpp_f<CTRL>(v.y),
                     dpp_f<CTRL>(v.z), dpp_f<CTRL>(v.w));
}

// twiddles per lane: tw[0..5] for stages M=8,16,32,64,128,256
__device__ __forceinline__ void make_tw(float2 tw[6], int lane, float sgn){
  float s,c;
  sincospif((float)(lane&3)*0.25f,&s,&c);     tw[0]=make_float2(c,sgn*s);
  sincospif((float)(lane&7)*0.125f,&s,&c);    tw[1]=make_float2(c,sgn*s);
  sincospif((float)(lane&15)*0.0625f,&s,&c);  tw[2]=make_float2(c,sgn*s);
  sincospif((float)(lane&31)*0.03125f,&s,&c); tw[3]=make_float2(c,sgn*s);
  sincospif((float)lane*(1.0f/64.0f),&s,&c);  tw[4]=make_float2(c,sgn*s);
  sincospif((float)lane*(1.0f/128.0f),&s,&c); tw[5]=make_float2(c,sgn*s);
}

// ---- cross-lane butterfly stages ----
__device__ __forceinline__ void fwd_stage_ds(float4 e[4], float2 W, int mask, int lane){
#pragma unroll
  for(int r=0;r<4;++r){
    float4 o = shfl_xor4(e[r],mask);
    float4 lo = c4add(e[r],o);
    float4 hi = c4mul(W,c4sub(o,e[r]));
    e[r] = (lane&mask)? hi : lo;
  }
}
template<int CTRL,int MASK>
__device__ __forceinline__ void fwd_stage_dpp(float4 e[4], float2 W, int lane){
#pragma unroll
  for(int r=0;r<4;++r){
    float4 o = dpp4<CTRL>(e[r]);
    float4 lo = c4add(e[r],o);
    float4 hi = c4mul(W,c4sub(o,e[r]));
    e[r] = (lane&MASK)? hi : lo;
  }
}
__device__ __forceinline__ void inv_stage_ds(float4 e[4], float2 W, int mask, int lane){
#pragma unroll
  for(int r=0;r<4;++r){
    float4 o = shfl_xor4(e[r],mask);
    bool hi = (lane&mask)!=0;
    float4 B = hi? e[r] : o;
    float4 A = hi? o : e[r];
    float4 t = c4mul(W,B);
    e[r] = hi? c4sub(A,t) : c4add(A,t);
  }
}
template<int CTRL,int MASK>
__device__ __forceinline__ void inv_stage_dpp(float4 e[4], float2 W, int lane){
#pragma unroll
  for(int r=0;r<4;++r){
    float4 o = dpp4<CTRL>(e[r]);
    bool hi = (lane&MASK)!=0;
    float4 B = hi? e[r] : o;
    float4 A = hi? o : e[r];
    float4 t = c4mul(W,B);
    e[r] = hi? c4sub(A,t) : c4add(A,t);
  }
}

// ---- forward 256-pt FFT ×2, DIF. Input: e[r] = x[64r+lane] (natural).
// Chunked natural-order store: at 4*brev6(lane), write {e0,e2,e1,e3}.
__device__ __forceinline__ void fftfwd4(float4 e[4], const float2 tw[6], int lane){
  float4 d,t;
  d = c4sub(e[0],e[2]); e[0]=c4add(e[0],e[2]); t = c4mul(tw[5],d);
  d = c4sub(e[1],e[3]); e[1]=c4add(e[1],e[3]); d = c4mul(tw[5],d);
  e[2]=t; e[3]=rotmi(d);
  d = c4sub(e[0],e[1]); e[0]=c4add(e[0],e[1]); e[1]=c4mul(tw[4],d);
  d = c4sub(e[2],e[3]); e[2]=c4add(e[2],e[3]); e[3]=c4mul(tw[4],d);
  fwd_stage_ds (e, tw[3], 32, lane);
  fwd_stage_ds (e, tw[2], 16, lane);
  fwd_stage_dpp<0x128,8>(e, tw[1], lane);
  fwd_stage_ds (e, tw[0], 4, lane);
  // s=2: W4^{lane&1} = 1 or -i
#pragma unroll
  for(int r=0;r<4;++r){
    float4 o = dpp4<0x4E>(e[r]);
    float4 lo = c4add(e[r],o);
    float4 d2 = c4sub(o,e[r]);
    if(lane&1) d2 = rotmi(d2);
    e[r] = (lane&2)? d2 : lo;
  }
  // s=1: W=1
#pragma unroll
  for(int r=0;r<4;++r){
    float4 o = dpp4<0xB1>(e[r]);
    e[r] = (lane&1)? c4sub(o,e[r]) : c4add(e[r],o);
  }
}

// ---- inverse 256-pt FFT ×2 (unnormalized), DIT. Chunked natural-order
// load at 4*brev6(lane): e0=c0, e1=c2, e2=c1, e3=c3. Output natural.
__device__ __forceinline__ void fftinv4(float4 e[4], const float2 tw[6], int lane){
#pragma unroll
  for(int r=0;r<4;++r){
    float4 o = dpp4<0xB1>(e[r]);
    e[r] = (lane&1)? c4sub(o,e[r]) : c4add(e[r],o);
  }
#pragma unroll
  for(int r=0;r<4;++r){
    float4 o = dpp4<0x4E>(e[r]);
    bool hi = (lane&2)!=0;
    float4 B = hi? e[r] : o;
    float4 A = hi? o : e[r];
    if(lane&1) B = rotpi(B);
    e[r] = hi? c4sub(A,B) : c4add(A,B);
  }
  inv_stage_ds (e, tw[0], 4, lane);
  inv_stage_dpp<0x128,8>(e, tw[1], lane);
  inv_stage_ds (e, tw[2], 16, lane);
  inv_stage_ds (e, tw[3], 32, lane);
  float4 t = c4mul(tw[4],e[1]); e[1]=c4sub(e[0],t); e[0]=c4add(e[0],t);
  t = c4mul(tw[4],e[3]); e[3]=c4sub(e[2],t); e[2]=c4add(e[2],t);
  t = c4mul(tw[5],e[2]); e[2]=c4sub(e[0],t); e[0]=c4add(e[0],t);
  t = c4mul(tw[5],e[3]); t = rotpi(t);
  e[3]=c4sub(e[1],t); e[1]=c4add(e[1],t);
}

// ---------- prep: psiP[j][v][u] = (f[u,v]+f[-u,-v])*0.5/rms[j], fp16, transposed
__global__ __launch_bounds__(256) void k_prep(const float* __restrict__ filt,
                                              const float* __restrict__ rms,
                                              __half* __restrict__ psiP){
  __shared__ float tile[32][257];
  int j = blockIdx.y, u0 = blockIdx.x<<5, tid = threadIdx.x;
  float rinv = 1.0f / rms[j];
  const float* fj = filt + (size_t)j*HW*HW;
#pragma unroll 4
  for(int k=0;k<32;++k){
    int u = u0+k, v = tid;
    int u2 = (HW-u)&255, v2 = (HW-v)&255;
    tile[k][v] = (fj[(size_t)u*HW+v] + fj[(size_t)u2*HW+v2])*0.5f*rinv;
  }
  __syncthreads();
  __half* pj = psiP + (size_t)j*HW*HW + u0;
#pragma unroll 4
  for(int it=0; it<32; ++it){
    int v = (it<<3) + (tid>>5), ul = tid&31;
    pj[(size_t)v*HW + ul] = __float2half(tile[ul][v]);
  }
}

// ---------- fwd rows: xc=(tg-pr)+i*ir, FFT over w -> X1[bc][h][v] (fp32) ----
__global__ __launch_bounds__(256) void k_fwd_rows(const float* __restrict__ tg,
                                                  const float* __restrict__ pr,
                                                  const float* __restrict__ ir,
                                                  float2* __restrict__ X1){
  int tid=threadIdx.x, lane=tid&63, wv=tid>>6;
  float2 tw[6]; make_tw(tw,lane,-1.0f);
  int bc = blockIdx.x>>5;
  int h0 = ((blockIdx.x&31)<<3) | (wv<<1);
  size_t b0 = ((size_t)bc*HW+h0)*HW;
  size_t b1 = b0 + HW;
  float4 e[4];
#pragma unroll
  for(int r=0;r<4;++r){
    int wd = lane+(r<<6);
    e[r] = make_float4(tg[b0+wd]-pr[b0+wd], ir[b0+wd],
                       tg[b1+wd]-pr[b1+wd], ir[b1+wd]);
  }
  fftfwd4(e,tw,lane);
  int cb = __brev((unsigned)lane)>>26;
  float4* d0 = (float4*)(X1 + b0 + (cb<<2));
  d0[0]=make_float4(e[0].x,e[0].y,e[2].x,e[2].y);
  d0[1]=make_float4(e[1].x,e[1].y,e[3].x,e[3].y);
  float4* d1 = (float4*)(X1 + b1 + (cb<<2));
  d1[0]=make_float4(e[0].z,e[0].w,e[2].z,e[2].w);
  d1[1]=make_float4(e[1].z,e[1].w,e[3].z,e[3].w);
}

// ---------- fwd cols: FFT over h, scale 1/65536 -> T2h[bc][v][u] (fp16) ----
__global__ __launch_bounds__(256) void k_fwd_cols(const float2* __restrict__ X1,
                                                  unsigned* __restrict__ T2h){
  int tid=threadIdx.x, lane=tid&63, wv=tid>>6;
  float2 tw[6]; make_tw(tw,lane,-1.0f);
  int bc = blockIdx.x>>5;
  int v0 = ((blockIdx.x&31)<<3) | (wv<<1);   // pair (v0, v0+1)
  float4 e[4];
#pragma unroll
  for(int r=0;r<4;++r)
    e[r] = *(const float4*)(X1 + ((size_t)bc*HW + (r<<6)+lane)*HW + v0);
  fftfwd4(e,tw,lane);
  const float s = 1.0f/65536.0f;
  int cb = __brev((unsigned)lane)>>26;
  unsigned* t0 = T2h + (size_t)bc*HW*HW + (size_t)v0*HW + (cb<<2);
  *(uint4*)t0 = make_uint4(f2h(make_float2(e[0].x*s,e[0].y*s)),
                           f2h(make_float2(e[2].x*s,e[2].y*s)),
                           f2h(make_float2(e[1].x*s,e[1].y*s)),
                           f2h(make_float2(e[3].x*s,e[3].y*s)));
  *(uint4*)(t0+HW) = make_uint4(f2h(make_float2(e[0].z*s,e[0].w*s)),
                                f2h(make_float2(e[2].z*s,e[2].w*s)),
                                f2h(make_float2(e[1].z*s,e[1].w*s)),
                                f2h(make_float2(e[3].z*s,e[3].w*s)));
}

// ---------- B1: Y = T2h*psiP, inverse FFT over u -> Zh[bcl*NF+j][h][v] fp16
__global__ __launch_bounds__(256) void k_b1(const unsigned* __restrict__ T2h,
                                            const __half* __restrict__ psiP,
                                            unsigned* __restrict__ Zh,
                                            int bc0){
  int tid=threadIdx.x, lane=tid&63, wv=tid>>6;
  float2 tw[6]; make_tw(tw,lane,+1.0f);
  int vt = blockIdx.x<<4;
  int j  = blockIdx.y;
  int bcl= blockIdx.z;
  int bc = bc0 + bcl;
  int cb = __brev((unsigned)lane)>>26;
  int u0 = cb<<2;
  int vb = vt + (wv<<2);
  const unsigned* tb  = T2h  + (size_t)bc*HW*HW + u0;
  const __half*   pjb = psiP + (size_t)j*HW*HW + u0;
  float4 ea[4], eb[4];
#pragma unroll
  for(int p=0;p<2;++p){
    int v0 = vb + (p<<1);
    uint4 tA = *(const uint4*)(tb + (size_t)v0*HW);
    uint4 tB = *(const uint4*)(tb + (size_t)(v0+1)*HW);
    uint2 puA = *(const uint2*)(pjb + (size_t)v0*HW);
    uint2 puB = *(const uint2*)(pjb + (size_t)(v0+1)*HW);
    float2 pA01 = h2f(puA.x), pA23 = h2f(puA.y);
    float2 pB01 = h2f(puB.x), pB23 = h2f(puB.y);
    float2 a0=h2f(tA.x), a1=h2f(tA.y), a2=h2f(tA.z), a3=h2f(tA.w);
    float2 c0=h2f(tB.x), c1=h2f(tB.y), c2=h2f(tB.z), c3=h2f(tB.w);
    float4* e = p? eb : ea;
    e[0]=make_float4(a0.x*pA01.x, a0.y*pA01.x, c0.x*pB01.x, c0.y*pB01.x);
    e[2]=make_float4(a1.x*pA01.y, a1.y*pA01.y, c1.x*pB01.y, c1.y*pB01.y);
    e[1]=make_float4(a2.x*pA23.x, a2.y*pA23.x, c2.x*pB23.x, c2.y*pB23.x);
    e[3]=make_float4(a3.x*pA23.y, a3.y*pA23.y, c3.x*pB23.y, c3.y*pB23.y);
    fftinv4(e,tw,lane);
  }
  unsigned* zb = Zh + (size_t)(bcl*NF + j)*HW*HW + vb;
#pragma unroll
  for(int r=0;r<4;++r){
    int h = (r<<6)+lane;
    *(uint4*)(zb + (size_t)h*HW) =
      make_uint4(f2h(make_float2(ea[r].x,ea[r].y)),
                 f2h(make_float2(ea[r].z,ea[r].w)),
                 f2h(make_float2(eb[r].x,eb[r].y)),
                 f2h(make_float2(eb[r].z,eb[r].w)));
  }
}

// ---------- B2: inverse FFT over v, pointwise R, transpose, partial sums ----
__global__ __launch_bounds__(256) void k_b2(const unsigned* __restrict__ Zh,
                                            float* __restrict__ out,
                                            double* __restrict__ part,
                                            int bc0){
  __shared__ float Rt[16*260];
  __shared__ double redS[4], redQ[4];
  int tid=threadIdx.x, lane=tid&63, wv=tid>>6;
  float2 tw[6]; make_tw(tw,lane,+1.0f);
  int h = blockIdx.x;
  int bcl = blockIdx.y;
  int bc = bc0 + bcl;
  int cb = __brev((unsigned)lane)>>26;
  float lsum=0.0f, lsq=0.0f;
  const unsigned* zb = Zh + (size_t)bcl*NF*HW*HW + (size_t)h*HW + (cb<<2);
  float* ob = out + (size_t)bc*(HW*HW*NF) + (size_t)h*(HW*NF);
  for(int jh=0;jh<2;++jh){
    if(jh) __syncthreads();
#pragma unroll
    for(int pp=0;pp<2;++pp){
      int jl0 = (wv<<2) + (pp<<1);
      int j0 = (jh<<4) + jl0;
      uint4 z0 = *(const uint4*)(zb + (size_t)j0*HW*HW);
      uint4 z1 = *(const uint4*)(zb + (size_t)(j0+1)*HW*HW);
      float2 a0=h2f(z0.x),a1=h2f(z0.y),a2=h2f(z0.z),a3=h2f(z0.w);
      float2 c0=h2f(z1.x),c1=h2f(z1.y),c2=h2f(z1.z),c3=h2f(z1.w);
      float4 e[4];
      e[0]=make_float4(a0.x,a0.y,c0.x,c0.y);
      e[2]=make_float4(a1.x,a1.y,c1.x,c1.y);
      e[1]=make_float4(a2.x,a2.y,c2.x,c2.y);
      e[3]=make_float4(a3.x,a3.y,c3.x,c3.y);
      fftinv4(e,tw,lane);
#pragma unroll
      for(int r=0;r<4;++r){
        int w = (r<<6)+lane;
        float t1 = fmaxf(fabsf(e[r].x)-e[r].y, 0.0f);
        float R0 = 1.0f - fmaxf(1.0f-t1, 0.0f);
        float t2 = fmaxf(fabsf(e[r].z)-e[r].w, 0.0f);
        float R1 = 1.0f - fmaxf(1.0f-t2, 0.0f);
        Rt[jl0*260 + w] = R0;
        Rt[(jl0+1)*260 + w] = R1;
        lsum += R0; lsum += R1;
        lsq = fmaf(R0,R0,lsq); lsq = fmaf(R1,R1,lsq);
      }
    }
    __syncthreads();
    float vals[16];
#pragma unroll
    for(int k=0;k<16;++k) vals[k]=Rt[k*260+tid];
    float4* dst = (float4*)(ob + (size_t)tid*NF + (jh<<4));
    dst[0]=make_float4(vals[0],vals[1],vals[2],vals[3]);
    dst[1]=make_float4(vals[4],vals[5],vals[6],vals[7]);
    dst[2]=make_float4(vals[8],vals[9],vals[10],vals[11]);
    dst[3]=make_float4(vals[12],vals[13],vals[14],vals[15]);
  }
#pragma unroll
  for(int m=32;m>=1;m>>=1){
    lsum += __shfl_xor(lsum,m,64);
    lsq  += __shfl_xor(lsq,m,64);
  }
  if(lane==0){ redS[wv]=(double)lsum; redQ[wv]=(double)lsq; }
  __syncthreads();
  if(tid==0){
    double S=redS[0]+redS[1]+redS[2]+redS[3];
    double Q=redQ[0]+redQ[1]+redQ[2]+redQ[3];
    part[((size_t)bc*HW+h)*2+0]=S;
    part[((size_t)bc*HW+h)*2+1]=Q;
  }
}

// ---------- finalize: deterministic mean/std (ddof=1) per batch ----------
__global__ __launch_bounds__(256) void k_fin(const double* __restrict__ part,
                                             float* __restrict__ out){
  __shared__ double red[256];
  int b = blockIdx.x, t = threadIdx.x;
  double s=0.0, q=0.0;
  for(int i=t;i<768;i+=256){
    s += part[((size_t)b*768+i)*2+0];
    q += part[((size_t)b*768+i)*2+1];
  }
  red[t]=s; __syncthreads();
  for(int k=128;k>0;k>>=1){ if(t<k) red[t]+=red[t+k]; __syncthreads(); }
  double S=red[0]; __syncthreads();
  red[t]=q; __syncthreads();
  for(int k=128;k>0;k>>=1){ if(t<k) red[t]+=red[t+k]; __syncthreads(); }
  if(t==0){
    const double N = 6291456.0;          // C*H*W*NF
    double m = S/N;
    double var = (red[0] - S*S/N)/(N-1.0);
    out[R_TOTAL+b] = (float)m;
    out[R_TOTAL+4+b] = (float)(var>0.0? sqrt(var):0.0);
  }
}

extern "C" void kernel_launch(void* const* d_in, const int* in_sizes, int n_in,
                              void* d_out, int out_size, void* d_ws, size_t ws_size,
                              hipStream_t stream){
  (void)in_sizes; (void)n_in; (void)out_size;
  const float* tg   = (const float*)d_in[0];
  const float* pr   = (const float*)d_in[1];
  const float* ir   = (const float*)d_in[2];
  const float* filt = (const float*)d_in[3];
  const float* rms  = (const float*)d_in[4];
  float* out = (float*)d_out;

  char* ws = (char*)d_ws;
  double* part = (double*)(ws + 128);
  size_t off = 128 + (size_t)BCN*HW*2*sizeof(double);              // part: 49 KB
  __half* psiP = (__half*)(ws + off);  off += (size_t)NF*HW*HW*2;  // 4.19 MB
  float2* X1   = (float2*)(ws + off);  off += (size_t)BCN*HW*HW*8; // 6.29 MB
  unsigned* T2h= (unsigned*)(ws + off);off += (size_t)BCN*HW*HW*4; // 3.15 MB
  unsigned* Zh = (unsigned*)(ws + off);
  const size_t fixedB = off;
  const size_t zPerBc = (size_t)NF*HW*HW*4;                        // 8.39 MB

  int bcc = 1;
  const int cand[6] = {12,6,4,3,2,1};
  for(int i=0;i<6;++i){
    if(fixedB + (size_t)cand[i]*zPerBc <= ws_size){ bcc = cand[i]; break; }
  }

  k_prep<<<dim3(8,NF), 256, 0, stream>>>(filt, rms, psiP);
  k_fwd_rows<<<dim3(BCN*32), 256, 0, stream>>>(tg, pr, ir, X1);
  k_fwd_cols<<<dim3(BCN*32), 256, 0, stream>>>(X1, T2h);

  int nch = BCN/bcc;
  for(int c=0;c<nch;++c){
    int bc0 = c*bcc;
    k_b1<<<dim3(16,NF,bcc), 256, 0, stream>>>(T2h, psiP, Zh, bc0);
    k_b2<<<dim3(HW,bcc), 256, 0, stream>>>(Zh, out, part, bc0);
  }
  k_fin<<<4, 256, 0, stream>>>(part, out);
}

// Round 5
// 130.360 us; speedup vs baseline: 2.3604x; 1.1527x over previous
//
#include <hip/hip_runtime.h>
#include <hip/hip_fp16.h>
#include <math.h>

#define HW 256
#define BCN 12                  // B*C
#define NF 32                   // filters used (last of 33 dropped)
#define R_TOTAL 25165824        // BCN*HW*HW*NF

// ---------------- fp16 pack helpers ----------------
__device__ __forceinline__ float2 h2f(unsigned u){
  return __half22float2(__builtin_bit_cast(__half2, u));
}
__device__ __forceinline__ unsigned f2h(float2 v){
  return __builtin_bit_cast(unsigned, __floats2half2_rn(v.x, v.y));
}

// ---------------- dual-complex (2-way ILP) helpers ----------------
// float4 = two independent complex values: (x,y) = FFT-A, (z,w) = FFT-B.
__device__ __forceinline__ float4 c4add(float4 a,float4 b){
  return make_float4(a.x+b.x,a.y+b.y,a.z+b.z,a.w+b.w);}
__device__ __forceinline__ float4 c4sub(float4 a,float4 b){
  return make_float4(a.x-b.x,a.y-b.y,a.z-b.z,a.w-b.w);}
__device__ __forceinline__ float4 c4mul(float2 w, float4 v){
  return make_float4(w.x*v.x - w.y*v.y, w.x*v.y + w.y*v.x,
                     w.x*v.z - w.y*v.w, w.x*v.w + w.y*v.z);}
// out = o + s*t  (s = per-lane +-1), select-free butterfly combine
__device__ __forceinline__ float4 fma4s(float s, float4 t, float4 o){
  return make_float4(fmaf(s,t.x,o.x), fmaf(s,t.y,o.y),
                     fmaf(s,t.z,o.z), fmaf(s,t.w,o.w));}
template<int SGN>
__device__ __forceinline__ float4 rots(float4 v){   // * SGN*i
  return (SGN>0) ? make_float4(-v.y,v.x,-v.w,v.z)
                 : make_float4(v.y,-v.x,v.w,-v.z);}
__device__ __forceinline__ float4 shfl_xor4(float4 v,int m){
  return make_float4(__shfl_xor(v.x,m,64),__shfl_xor(v.y,m,64),
                     __shfl_xor(v.z,m,64),__shfl_xor(v.w,m,64));}

// ---- DPP lane exchange (VALU pipe): xor1=quad_perm(1,0,3,2)=0xB1,
// xor2=quad_perm(2,3,0,1)=0x4E, xor8=row_ror:8=0x128 ----
template<int CTRL>
__device__ __forceinline__ float dpp_f(float x){
  return __builtin_bit_cast(float,
    __builtin_amdgcn_update_dpp(0, __builtin_bit_cast(int, x), CTRL, 0xF, 0xF, true));
}
template<int CTRL>
__device__ __forceinline__ float4 dpp4(float4 v){
  return make_float4(dpp_f<CTRL>(v.x), dpp_f<CTRL>(v.y),
                     dpp_f<CTRL>(v.z), dpp_f<CTRL>(v.w));
}

// ---- per-lane twiddles: V_m = (lane&m)? W_{2m}^{lane&(m-1)} : 1 ----
struct Tw {
  float2 V2,V4,V8,V16,V32,t64,t128;
  float s1,s2,s4,s8,s16,s32;
};
template<int SGN>
__device__ __forceinline__ void make_tw(Tw &T, int lane){
  const float g = (SGN>0)? 1.0f : -1.0f;
  float s,c;
  sincospif((float)(lane&1)*0.5f,&s,&c);
  T.V2  = (lane&2)?  make_float2(c,g*s) : make_float2(1.f,0.f);
  sincospif((float)(lane&3)*0.25f,&s,&c);
  T.V4  = (lane&4)?  make_float2(c,g*s) : make_float2(1.f,0.f);
  sincospif((float)(lane&7)*0.125f,&s,&c);
  T.V8  = (lane&8)?  make_float2(c,g*s) : make_float2(1.f,0.f);
  sincospif((float)(lane&15)*0.0625f,&s,&c);
  T.V16 = (lane&16)? make_float2(c,g*s) : make_float2(1.f,0.f);
  sincospif((float)(lane&31)*0.03125f,&s,&c);
  T.V32 = (lane&32)? make_float2(c,g*s) : make_float2(1.f,0.f);
  sincospif((float)lane*(1.0f/64.0f),&s,&c);  T.t64 = make_float2(c,g*s);
  sincospif((float)lane*(1.0f/128.0f),&s,&c); T.t128= make_float2(c,g*s);
  T.s1=(lane&1)?-1.f:1.f;  T.s2=(lane&2)?-1.f:1.f;  T.s4=(lane&4)?-1.f:1.f;
  T.s8=(lane&8)?-1.f:1.f;  T.s16=(lane&16)?-1.f:1.f; T.s32=(lane&32)?-1.f:1.f;
}

// ---- unified 256-pt FFT x2 (DIT, select-free). Input: chunk c[0..3] at
// float index 4*brev6(lane): e0=c0, e1=c2, e2=c1, e3=c3. Output: e[r] holds
// X[64r+lane] (natural order). SGN=-1 forward DFT, SGN=+1 inverse (unnorm).
template<int SGN>
__device__ __forceinline__ void fft4(float4 e[4], const Tw &T){
  // mask1 (V=1)
#pragma unroll
  for(int r=0;r<4;++r){
    float4 o = dpp4<0xB1>(e[r]);
    e[r] = fma4s(T.s1, e[r], o);
  }
  // mask2 (DPP)
#pragma unroll
  for(int r=0;r<4;++r){
    float4 t = c4mul(T.V2, e[r]);
    float4 o = dpp4<0x4E>(t);
    e[r] = fma4s(T.s2, t, o);
  }
  // mask4 (DS)
#pragma unroll
  for(int r=0;r<4;++r){
    float4 t = c4mul(T.V4, e[r]);
    float4 o = shfl_xor4(t,4);
    e[r] = fma4s(T.s4, t, o);
  }
  // mask8 (DPP row_ror:8)
#pragma unroll
  for(int r=0;r<4;++r){
    float4 t = c4mul(T.V8, e[r]);
    float4 o = dpp4<0x128>(t);
    e[r] = fma4s(T.s8, t, o);
  }
  // mask16 (DS)
#pragma unroll
  for(int r=0;r<4;++r){
    float4 t = c4mul(T.V16, e[r]);
    float4 o = shfl_xor4(t,16);
    e[r] = fma4s(T.s16, t, o);
  }
  // mask32 (DS)
#pragma unroll
  for(int r=0;r<4;++r){
    float4 t = c4mul(T.V32, e[r]);
    float4 o = shfl_xor4(t,32);
    e[r] = fma4s(T.s32, t, o);
  }
  // len128: pairs (0,1),(2,3), twiddle W_128^lane
  float4 t = c4mul(T.t64, e[1]); e[1]=c4sub(e[0],t); e[0]=c4add(e[0],t);
  t = c4mul(T.t64, e[3]); e[3]=c4sub(e[2],t); e[2]=c4add(e[2],t);
  // len256: pairs (0,2),(1,3); pair (1,3) twiddle W_256^{lane+64} = t128*SGN*i
  t = c4mul(T.t128, e[2]); e[2]=c4sub(e[0],t); e[0]=c4add(e[0],t);
  t = c4mul(T.t128, e[3]); t = rots<SGN>(t);
  e[3]=c4sub(e[1],t); e[1]=c4add(e[1],t);
}

// ---------- prep: psiP[j][v][u] = (f[u,v]+f[-u,-v])*0.5/rms[j], fp16, transposed
__global__ __launch_bounds__(256) void k_prep(const float* __restrict__ filt,
                                              const float* __restrict__ rms,
                                              __half* __restrict__ psiP){
  __shared__ float tile[32][257];
  int j = blockIdx.y, u0 = blockIdx.x<<5, tid = threadIdx.x;
  float rinv = 1.0f / rms[j];
  const float* fj = filt + (size_t)j*HW*HW;
#pragma unroll 4
  for(int k=0;k<32;++k){
    int u = u0+k, v = tid;
    int u2 = (HW-u)&255, v2 = (HW-v)&255;
    tile[k][v] = (fj[(size_t)u*HW+v] + fj[(size_t)u2*HW+v2])*0.5f*rinv;
  }
  __syncthreads();
  __half* pj = psiP + (size_t)j*HW*HW + u0;
#pragma unroll 4
  for(int it=0; it<32; ++it){
    int v = (it<<3) + (tid>>5), ul = tid&31;
    pj[(size_t)v*HW + ul] = __float2half(tile[ul][v]);
  }
}

// ---------- fwd rows: xc=(tg-pr)+i*ir, DIT FFT over w -> X1[bc][h][v] natural
__global__ __launch_bounds__(256) void k_fwd_rows(const float* __restrict__ tg,
                                                  const float* __restrict__ pr,
                                                  const float* __restrict__ ir,
                                                  float2* __restrict__ X1){
  int tid=threadIdx.x, lane=tid&63, wv=tid>>6;
  Tw T; make_tw<-1>(T,lane);
  int bc = blockIdx.x>>5;
  int h0 = ((blockIdx.x&31)<<3) | (wv<<1);
  size_t b0 = ((size_t)bc*HW+h0)*HW;
  size_t b1 = b0 + HW;
  int cb4 = (int)((__brev((unsigned)lane)>>26)<<2);
  float4 t0 = *(const float4*)(tg+b0+cb4);
  float4 p0 = *(const float4*)(pr+b0+cb4);
  float4 i0 = *(const float4*)(ir+b0+cb4);
  float4 t1 = *(const float4*)(tg+b1+cb4);
  float4 p1 = *(const float4*)(pr+b1+cb4);
  float4 i1 = *(const float4*)(ir+b1+cb4);
  float4 e[4];
  e[0]=make_float4(t0.x-p0.x, i0.x, t1.x-p1.x, i1.x);
  e[2]=make_float4(t0.y-p0.y, i0.y, t1.y-p1.y, i1.y);
  e[1]=make_float4(t0.z-p0.z, i0.z, t1.z-p1.z, i1.z);
  e[3]=make_float4(t0.w-p0.w, i0.w, t1.w-p1.w, i1.w);
  fft4<-1>(e,T);
#pragma unroll
  for(int r=0;r<4;++r){
    X1[b0 + (r<<6)+lane] = make_float2(e[r].x,e[r].y);
    X1[b1 + (r<<6)+lane] = make_float2(e[r].z,e[r].w);
  }
}

// ---------- fwd cols: DIT FFT over h, scale 1/65536 -> T2h[bc][v][u] fp16 natural
__global__ __launch_bounds__(256) void k_fwd_cols(const float2* __restrict__ X1,
                                                  unsigned* __restrict__ T2h){
  int tid=threadIdx.x, lane=tid&63, wv=tid>>6;
  Tw T; make_tw<-1>(T,lane);
  int bc = blockIdx.x>>5;
  int v0 = ((blockIdx.x&31)<<3) | (wv<<1);   // column pair (v0, v0+1)
  int b4 = (int)((__brev((unsigned)lane)>>26)<<2);
  const float2* xb = X1 + (size_t)bc*HW*HW + v0;
  float4 L0 = *(const float4*)(xb + (size_t)(b4+0)*HW);
  float4 L1 = *(const float4*)(xb + (size_t)(b4+1)*HW);
  float4 L2 = *(const float4*)(xb + (size_t)(b4+2)*HW);
  float4 L3 = *(const float4*)(xb + (size_t)(b4+3)*HW);
  float4 e[4];
  e[0]=L0; e[2]=L1; e[1]=L2; e[3]=L3;
  fft4<-1>(e,T);
  const float s = 1.0f/65536.0f;
  unsigned* t0 = T2h + (size_t)bc*HW*HW + (size_t)v0*HW;
#pragma unroll
  for(int r=0;r<4;++r){
    int u = (r<<6)+lane;
    t0[u]    = f2h(make_float2(e[r].x*s, e[r].y*s));
    t0[HW+u] = f2h(make_float2(e[r].z*s, e[r].w*s));
  }
}

// ---------- B1: Y = T2h*psiP, inverse FFT over u -> Zh[bcl*NF+j][h][v] fp16
__global__ __launch_bounds__(256) void k_b1(const unsigned* __restrict__ T2h,
                                            const __half* __restrict__ psiP,
                                            unsigned* __restrict__ Zh,
                                            int bc0){
  int tid=threadIdx.x, lane=tid&63, wv=tid>>6;
  Tw T; make_tw<1>(T,lane);
  int vt = blockIdx.x<<4;
  int j  = blockIdx.y;
  int bcl= blockIdx.z;
  int bc = bc0 + bcl;
  int cb = __brev((unsigned)lane)>>26;
  int u0 = cb<<2;
  int vb = vt + (wv<<2);
  const unsigned* tb  = T2h  + (size_t)bc*HW*HW + u0;
  const __half*   pjb = psiP + (size_t)j*HW*HW + u0;
  float4 ea[4], eb[4];
#pragma unroll
  for(int p=0;p<2;++p){
    int v0 = vb + (p<<1);
    uint4 tA = *(const uint4*)(tb + (size_t)v0*HW);
    uint4 tB = *(const uint4*)(tb + (size_t)(v0+1)*HW);
    uint2 puA = *(const uint2*)(pjb + (size_t)v0*HW);
    uint2 puB = *(const uint2*)(pjb + (size_t)(v0+1)*HW);
    float2 pA01 = h2f(puA.x), pA23 = h2f(puA.y);
    float2 pB01 = h2f(puB.x), pB23 = h2f(puB.y);
    float2 a0=h2f(tA.x), a1=h2f(tA.y), a2=h2f(tA.z), a3=h2f(tA.w);
    float2 c0=h2f(tB.x), c1=h2f(tB.y), c2=h2f(tB.z), c3=h2f(tB.w);
    float4* e = p? eb : ea;
    e[0]=make_float4(a0.x*pA01.x, a0.y*pA01.x, c0.x*pB01.x, c0.y*pB01.x);
    e[2]=make_float4(a1.x*pA01.y, a1.y*pA01.y, c1.x*pB01.y, c1.y*pB01.y);
    e[1]=make_float4(a2.x*pA23.x, a2.y*pA23.x, c2.x*pB23.x, c2.y*pB23.x);
    e[3]=make_float4(a3.x*pA23.y, a3.y*pA23.y, c3.x*pB23.y, c3.y*pB23.y);
    fft4<1>(e,T);
  }
  unsigned* zb = Zh + (size_t)(bcl*NF + j)*HW*HW + vb;
#pragma unroll
  for(int r=0;r<4;++r){
    int h = (r<<6)+lane;
    *(uint4*)(zb + (size_t)h*HW) =
      make_uint4(f2h(make_float2(ea[r].x,ea[r].y)),
                 f2h(make_float2(ea[r].z,ea[r].w)),
                 f2h(make_float2(eb[r].x,eb[r].y)),
                 f2h(make_float2(eb[r].z,eb[r].w)));
  }
}

// ---------- B2: inverse FFT over v, pointwise R, transpose, partial sums ----
__global__ __launch_bounds__(256) void k_b2(const unsigned* __restrict__ Zh,
                                            float* __restrict__ out,
                                            double* __restrict__ part,
                                            int bc0){
  __shared__ float Rt[16*260];
  __shared__ double redS[4], redQ[4];
  int tid=threadIdx.x, lane=tid&63, wv=tid>>6;
  Tw T; make_tw<1>(T,lane);
  int h = blockIdx.x;
  int bcl = blockIdx.y;
  int bc = bc0 + bcl;
  int cb = __brev((unsigned)lane)>>26;
  float lsum=0.0f, lsq=0.0f;
  const unsigned* zb = Zh + (size_t)bcl*NF*HW*HW + (size_t)h*HW + (cb<<2);
  float* ob = out + (size_t)bc*(HW*HW*NF) + (size_t)h*(HW*NF);
  for(int jh=0;jh<2;++jh){
    if(jh) __syncthreads();
#pragma unroll
    for(int pp=0;pp<2;++pp){
      int jl0 = (wv<<2) + (pp<<1);
      int j0 = (jh<<4) + jl0;
      uint4 z0 = *(const uint4*)(zb + (size_t)j0*HW*HW);
      uint4 z1 = *(const uint4*)(zb + (size_t)(j0+1)*HW*HW);
      float2 a0=h2f(z0.x),a1=h2f(z0.y),a2=h2f(z0.z),a3=h2f(z0.w);
      float2 c0=h2f(z1.x),c1=h2f(z1.y),c2=h2f(z1.z),c3=h2f(z1.w);
      float4 e[4];
      e[0]=make_float4(a0.x,a0.y,c0.x,c0.y);
      e[2]=make_float4(a1.x,a1.y,c1.x,c1.y);
      e[1]=make_float4(a2.x,a2.y,c2.x,c2.y);
      e[3]=make_float4(a3.x,a3.y,c3.x,c3.y);
      fft4<1>(e,T);
#pragma unroll
      for(int r=0;r<4;++r){
        int w = (r<<6)+lane;
        float t1 = fmaxf(fabsf(e[r].x)-e[r].y, 0.0f);
        float R0 = 1.0f - fmaxf(1.0f-t1, 0.0f);
        float t2 = fmaxf(fabsf(e[r].z)-e[r].w, 0.0f);
        float R1 = 1.0f - fmaxf(1.0f-t2, 0.0f);
        Rt[jl0*260 + w] = R0;
        Rt[(jl0+1)*260 + w] = R1;
        lsum += R0; lsum += R1;
        lsq = fmaf(R0,R0,lsq); lsq = fmaf(R1,R1,lsq);
      }
    }
    __syncthreads();
    float vals[16];
#pragma unroll
    for(int k=0;k<16;++k) vals[k]=Rt[k*260+tid];
    float4* dst = (float4*)(ob + (size_t)tid*NF + (jh<<4));
    dst[0]=make_float4(vals[0],vals[1],vals[2],vals[3]);
    dst[1]=make_float4(vals[4],vals[5],vals[6],vals[7]);
    dst[2]=make_float4(vals[8],vals[9],vals[10],vals[11]);
    dst[3]=make_float4(vals[12],vals[13],vals[14],vals[15]);
  }
#pragma unroll
  for(int m=32;m>=1;m>>=1){
    lsum += __shfl_xor(lsum,m,64);
    lsq  += __shfl_xor(lsq,m,64);
  }
  if(lane==0){ redS[wv]=(double)lsum; redQ[wv]=(double)lsq; }
  __syncthreads();
  if(tid==0){
    double S=redS[0]+redS[1]+redS[2]+redS[3];
    double Q=redQ[0]+redQ[1]+redQ[2]+redQ[3];
    part[((size_t)bc*HW+h)*2+0]=S;
    part[((size_t)bc*HW+h)*2+1]=Q;
  }
}

// ---------- finalize: deterministic mean/std (ddof=1) per batch ----------
__global__ __launch_bounds__(256) void k_fin(const double* __restrict__ part,
                                             float* __restrict__ out){
  __shared__ double red[256];
  int b = blockIdx.x, t = threadIdx.x;
  double s=0.0, q=0.0;
  for(int i=t;i<768;i+=256){
    s += part[((size_t)b*768+i)*2+0];
    q += part[((size_t)b*768+i)*2+1];
  }
  red[t]=s; __syncthreads();
  for(int k=128;k>0;k>>=1){ if(t<k) red[t]+=red[t+k]; __syncthreads(); }
  double S=red[0]; __syncthreads();
  red[t]=q; __syncthreads();
  for(int k=128;k>0;k>>=1){ if(t<k) red[t]+=red[t+k]; __syncthreads(); }
  if(t==0){
    const double N = 6291456.0;          // C*H*W*NF
    double m = S/N;
    double var = (red[0] - S*S/N)/(N-1.0);
    out[R_TOTAL+b] = (float)m;
    out[R_TOTAL+4+b] = (float)(var>0.0? sqrt(var):0.0);
  }
}

extern "C" void kernel_launch(void* const* d_in, const int* in_sizes, int n_in,
                              void* d_out, int out_size, void* d_ws, size_t ws_size,
                              hipStream_t stream){
  (void)in_sizes; (void)n_in; (void)out_size;
  const float* tg   = (const float*)d_in[0];
  const float* pr   = (const float*)d_in[1];
  const float* ir   = (const float*)d_in[2];
  const float* filt = (const float*)d_in[3];
  const float* rms  = (const float*)d_in[4];
  float* out = (float*)d_out;

  char* ws = (char*)d_ws;
  double* part = (double*)(ws + 128);
  size_t off = 128 + (size_t)BCN*HW*2*sizeof(double);              // part: 49 KB
  __half* psiP = (__half*)(ws + off);  off += (size_t)NF*HW*HW*2;  // 4.19 MB
  float2* X1   = (float2*)(ws + off);  off += (size_t)BCN*HW*HW*8; // 6.29 MB
  unsigned* T2h= (unsigned*)(ws + off);off += (size_t)BCN*HW*HW*4; // 3.15 MB
  unsigned* Zh = (unsigned*)(ws + off);
  const size_t fixedB = off;
  const size_t zPerBc = (size_t)NF*HW*HW*4;                        // 8.39 MB

  int bcc = 1;
  const int cand[6] = {12,6,4,3,2,1};
  for(int i=0;i<6;++i){
    if(fixedB + (size_t)cand[i]*zPerBc <= ws_size){ bcc = cand[i]; break; }
  }

  k_prep<<<dim3(8,NF), 256, 0, stream>>>(filt, rms, psiP);
  k_fwd_rows<<<dim3(BCN*32), 256, 0, stream>>>(tg, pr, ir, X1);
  k_fwd_cols<<<dim3(BCN*32), 256, 0, stream>>>(X1, T2h);

  int nch = BCN/bcc;
  for(int c=0;c<nch;++c){
    int bc0 = c*bcc;
    k_b1<<<dim3(16,NF,bcc), 256, 0, stream>>>(T2h, psiP, Zh, bc0);
    k_b2<<<dim3(HW,bcc), 256, 0, stream>>>(Zh, out, part, bc0);
  }
  k_fin<<<4, 256, 0, stream>>>(part, out);
}